// Round 5
// baseline (6039.114 us; speedup 1.0000x reference)
//
#include <hip/hip_runtime.h>
#include <cstdint>

constexpr int BB = 128;   // batch
constexpr int SS = 512;   // source length
constexpr int DD = 512;   // hidden dim
constexpr int TT = 64;    // decode steps
constexpr int OO = 3;     // output dim

constexpr float C2LE = 2.8853900817779268f;  // 2*log2(e)

typedef __attribute__((ext_vector_type(8))) short bf16x8;
typedef __attribute__((ext_vector_type(4))) float f32x4;

__device__ __forceinline__ float tanh_fast(float x) {
  float e = __expf(2.0f * x);
  return 1.0f - 2.0f / (e + 1.0f);
}
__device__ __forceinline__ float sigmoid_fast(float x) {
  return 1.0f / (1.0f + __expf(-x));
}
__device__ __forceinline__ unsigned short f2bf(float f) {
  uint32_t u = __float_as_uint(f);
  uint32_t r = (u + 0x7FFFu + ((u >> 16) & 1u)) >> 16;  // RNE
  return (unsigned short)r;
}
__device__ __forceinline__ float bf2f(unsigned short h) {
  return __uint_as_float((uint32_t)h << 16);
}
__device__ __forceinline__ float2 bfx2(uint32_t u) {
  float2 r;
  r.x = __uint_as_float(u << 16);
  r.y = __uint_as_float(u & 0xFFFF0000u);
  return r;
}
__device__ __forceinline__ float fexp2(float x) {
#if __has_builtin(__builtin_amdgcn_exp2f)
  return __builtin_amdgcn_exp2f(x);
#else
  return exp2f(x);
#endif
}
__device__ __forceinline__ float frcp(float x) {
#if __has_builtin(__builtin_amdgcn_rcpf)
  return __builtin_amdgcn_rcpf(x);
#else
  return 1.0f / x;
#endif
}

// ---------------------------------------------------------------------------
// MFMA bf16 GEMM: Uk2 = bf16( C2LE * (e_bf @ Ua_bf^T + bu) )   [B*S x D]
// ---------------------------------------------------------------------------
__global__ __launch_bounds__(256) void gemm_uk_mfma(
    const unsigned short* __restrict__ A, const unsigned short* __restrict__ Bw,
    const float* __restrict__ bias, unsigned short* __restrict__ Uk) {
  __shared__ unsigned short Asb[128 * 40];
  __shared__ unsigned short Bsb[128 * 40];
  const int tid = threadIdx.x;
  const int m0 = blockIdx.y * 128, n0 = blockIdx.x * 128;
  const int w = tid >> 6, l = tid & 63;
  const int wr = w >> 1, wc = w & 1;
  const int lm = l & 15, kg = l >> 4;

  f32x4 acc[4][4] = {};

  for (int kc = 0; kc < 512; kc += 32) {
    uint4 av[2], bv[2];
#pragma unroll
    for (int p = 0; p < 2; ++p) {
      int u = tid + p * 256;
      int r = u >> 2, ko = (u & 3) * 8;
      av[p] = *(const uint4*)(A + (size_t)(m0 + r) * 512 + kc + ko);
      bv[p] = *(const uint4*)(Bw + (size_t)(n0 + r) * 512 + kc + ko);
    }
    __syncthreads();
#pragma unroll
    for (int p = 0; p < 2; ++p) {
      int u = tid + p * 256;
      int r = u >> 2, ko = (u & 3) * 8;
      *(uint4*)&Asb[r * 40 + ko] = av[p];
      *(uint4*)&Bsb[r * 40 + ko] = bv[p];
    }
    __syncthreads();
    bf16x8 af[4], bfr[4];
#pragma unroll
    for (int i = 0; i < 4; ++i) {
      af[i]  = *(const bf16x8*)&Asb[(wr * 64 + i * 16 + lm) * 40 + kg * 8];
      bfr[i] = *(const bf16x8*)&Bsb[(wc * 64 + i * 16 + lm) * 40 + kg * 8];
    }
#pragma unroll
    for (int i = 0; i < 4; ++i)
#pragma unroll
      for (int j = 0; j < 4; ++j)
        acc[i][j] = __builtin_amdgcn_mfma_f32_16x16x32_bf16(af[i], bfr[j],
                                                            acc[i][j], 0, 0, 0);
  }

  const int row_base = m0 + wr * 64;
  const int col_base = n0 + wc * 64;
#pragma unroll
  for (int j = 0; j < 4; ++j) {
    const int col = col_base + j * 16 + lm;
    const float bu = bias[col];
#pragma unroll
    for (int i = 0; i < 4; ++i) {
      const int r0 = row_base + i * 16 + kg * 4;
#pragma unroll
      for (int rr = 0; rr < 4; ++rr)
        Uk[(size_t)(r0 + rr) * 512 + col] = f2bf(C2LE * (acc[i][j][rr] + bu));
    }
  }
}

// fp32 -> bf16, 8 elems/thread
__global__ __launch_bounds__(256) void conv_bf(const float* __restrict__ in,
                                               unsigned short* __restrict__ outp) {
  size_t idx = ((size_t)blockIdx.x * 256 + threadIdx.x) * 8;
  const float4* p = (const float4*)(in + idx);
  float4 a = p[0], b = p[1];
  uint4 r;
  r.x = f2bf(a.x) | ((uint32_t)f2bf(a.y) << 16);
  r.y = f2bf(a.z) | ((uint32_t)f2bf(a.w) << 16);
  r.z = f2bf(b.x) | ((uint32_t)f2bf(b.y) << 16);
  r.w = f2bf(b.z) | ((uint32_t)f2bf(b.w) << 16);
  *(uint4*)(outp + idx) = r;
}

// Wq2t[k*512 + j] = bf16(C2LE * Wa[j][k])   (transposed, k-major)
__global__ void prep_wq2t(const float* __restrict__ Wa,
                          unsigned short* __restrict__ Wq2t) {
  int idx = blockIdx.x * 256 + threadIdx.x;  // 512*512 : idx = k*512 + j
  int k = idx >> 9, j = idx & 511;
  Wq2t[idx] = f2bf(C2LE * Wa[(size_t)j * DD + k]);
}

// Wih3[row'][k], row' = dgrp*48 + gate*16 + dl  <-  W_ih[gate*512+dgrp*16+dl][k]
__global__ void prep_wih3(const float* __restrict__ W_ih,
                          unsigned short* __restrict__ Wih3) {
  int idx = blockIdx.x * 256 + threadIdx.x;  // 1536*512
  int rp = idx >> 9, k = idx & 511;
  int dgrp = rp / 48, rem = rp % 48;
  int g = rem >> 4, dl = rem & 15;
  int src = g * 512 + dgrp * 16 + dl;
  Wih3[idx] = f2bf(W_ih[(size_t)src * (DD + OO) + k]);
}

// Whh3 same layout from W_hh (ld 512)
__global__ void prep_whh3(const float* __restrict__ Whh,
                          unsigned short* __restrict__ Whh3) {
  int idx = blockIdx.x * 256 + threadIdx.x;  // 1536*512
  int rp = idx >> 9, k = idx & 511;
  int dgrp = rp / 48, rem = rp % 48;
  int g = rem >> 4, dl = rem & 15;
  int src = g * 512 + dgrp * 16 + dl;
  Whh3[idx] = f2bf(Whh[(size_t)src * DD + k]);
}

__global__ void prep_bq(const float* __restrict__ ba, float* __restrict__ bq) {
  int j = blockIdx.x * 256 + threadIdx.x;  // 512
  bq[j] = C2LE * ba[j];
}

// init: h = e_last -> out_hT (f32 master) + h2 (bf16 hi|lo)
__global__ void init_h(const float* __restrict__ e_last,
                       float* __restrict__ out_hT,
                       unsigned short* __restrict__ h2g) {
  int idx = blockIdx.x * 256 + threadIdx.x;  // 128*512
  int b = idx >> 9, d = idx & 511;
  float v = e_last[idx];
  out_hT[idx] = v;
  unsigned short hi = f2bf(v);
  h2g[(size_t)b * 1024 + d] = hi;
  h2g[(size_t)b * 1024 + 512 + d] = f2bf(v - bf2f(hi));
}

// ---------------------------------------------------------------------------
// K_att: blocks 0..255 = (b, shalf). Per block:
//   1. q2 = h(f32) @ Wq2t + bq  (redundant GEMV, Wq2t L2-resident)
//   2. y[s] = -2 * sum_d va[d] / (1 + 2^(q2[d]+Uk2[b,s,d])) for own 256 s
//   3. local softmax: (m, l) -> stats; u = exp(y - m) -> uw
//   4. partial ctx (unnormalized) -> ctxp[b][shalf]
// Block 256: out_d[:, t-1] = h @ W_out^T + b_out
// ---------------------------------------------------------------------------
__global__ __launch_bounds__(512) void attn_fused(
    const unsigned short* __restrict__ Uk2, const unsigned short* __restrict__ e_bf,
    const unsigned short* __restrict__ Wq2t, const float* __restrict__ bq,
    const float* __restrict__ va, const float* __restrict__ out_hT,
    float* __restrict__ ctxp, float* __restrict__ stats, float* __restrict__ uw,
    const float* __restrict__ W_out, const float* __restrict__ b_out,
    float* __restrict__ out_d, int t) {
  const int blk = blockIdx.x, tid = threadIdx.x;
  if (blk == 256) {
    if (t > 0) {
      const int b = tid >> 2, g4 = tid & 3;
      const float* hp = out_hT + (size_t)b * DD + g4 * 128;
#pragma unroll
      for (int o = 0; o < OO; ++o) {
        const float* wrow = W_out + (size_t)o * DD + g4 * 128;
        float acc = 0.f;
#pragma unroll 8
        for (int i = 0; i < 128; ++i) acc += hp[i] * wrow[i];
        acc += __shfl_down(acc, 2, 4);
        acc += __shfl_down(acc, 1, 4);
        if (g4 == 0) out_d[((size_t)b * TT + (t - 1)) * OO + o] = acc + b_out[o];
      }
    }
    return;
  }
  const int b = blk >> 1, shalf = blk & 1;

  __shared__ float h_s[512];
  __shared__ float qv_s[4 * 132];
  __shared__ float va_s[4 * 132];
  __shared__ float u_s[256];
  __shared__ float red_s[16];
  __shared__ float part[8 * 520];

  h_s[tid] = out_hT[(size_t)b * DD + tid];
  va_s[(tid >> 7) * 132 + (tid & 127)] = va[tid];
  __syncthreads();

  // ---- 1. q2 GEMV (1 col per thread, k-major coalesced)
  {
    float acc = 0.f;
    const unsigned short* wp = Wq2t + tid;
#pragma unroll 8
    for (int k = 0; k < 512; ++k) acc += h_s[k] * bf2f(wp[(size_t)k * 512]);
    acc += bq[tid];
    qv_s[(tid >> 7) * 132 + (tid & 127)] = acc;
  }
  __syncthreads();

  // ---- 2. scores for own 256 s (2 threads per s, 256 d each)
  {
    const int sl = tid >> 1, hf = tid & 1;
    const uint4* up =
        (const uint4*)(Uk2 + ((size_t)b * SS + shalf * 256 + sl) * DD + hf * 256);
    float acc = 0.f;
#pragma unroll 4
    for (int j = 0; j < 32; ++j) {
      uint4 u = up[j];
      const int qq = (hf << 1) + (j >> 4), jj = j & 15;
      const float* qb = &qv_s[qq * 132 + jj * 8];
      const float* vb = &va_s[qq * 132 + jj * 8];
      float4 q0 = *(const float4*)&qb[0], q1 = *(const float4*)&qb[4];
      float4 v0 = *(const float4*)&vb[0], v1 = *(const float4*)&vb[4];
      float2 e0 = bfx2(u.x), e1 = bfx2(u.y), e2 = bfx2(u.z), e3 = bfx2(u.w);
      acc += v0.x * frcp(1.f + fexp2(q0.x + e0.x));
      acc += v0.y * frcp(1.f + fexp2(q0.y + e0.y));
      acc += v0.z * frcp(1.f + fexp2(q0.z + e1.x));
      acc += v0.w * frcp(1.f + fexp2(q0.w + e1.y));
      acc += v1.x * frcp(1.f + fexp2(q1.x + e2.x));
      acc += v1.y * frcp(1.f + fexp2(q1.y + e2.y));
      acc += v1.z * frcp(1.f + fexp2(q1.z + e3.x));
      acc += v1.w * frcp(1.f + fexp2(q1.w + e3.y));
    }
    acc += __shfl_xor(acc, 1);
    if (hf == 0) u_s[sl] = -2.f * acc;
  }
  __syncthreads();

  // ---- 3. local softmax stats (values live in waves 0..3)
  {
    const int w4 = tid >> 6;
    float y = (tid < 256) ? u_s[tid] : -3.0e38f;
    float m = y;
#pragma unroll
    for (int off = 32; off; off >>= 1) m = fmaxf(m, __shfl_xor(m, off));
    if (w4 < 4 && (tid & 63) == 0) red_s[w4] = m;
    __syncthreads();
    const float gm = fmaxf(fmaxf(red_s[0], red_s[1]), fmaxf(red_s[2], red_s[3]));
    float e = (tid < 256) ? __expf(y - gm) : 0.f;
    float sm = e;
#pragma unroll
    for (int off = 32; off; off >>= 1) sm += __shfl_xor(sm, off);
    if (w4 < 4 && (tid & 63) == 0) red_s[8 + w4] = sm;
    __syncthreads();
    if (tid < 256) {
      u_s[tid] = e;
      uw[(size_t)b * SS + shalf * 256 + tid] = e;
    }
    if (tid == 0) {
      stats[b * 4 + shalf * 2] = gm;
      stats[b * 4 + shalf * 2 + 1] = red_s[8] + red_s[9] + red_s[10] + red_s[11];
    }
  }
  __syncthreads();

  // ---- 4. partial ctx over own 256 s (8 s-groups x 64 d-slots of 8)
  {
    const int dsl = tid & 63, sg = tid >> 6;
    const unsigned short* eb =
        e_bf + ((size_t)b * SS + shalf * 256 + sg * 32) * DD + dsl * 8;
    float a0 = 0.f, a1 = 0.f, a2 = 0.f, a3 = 0.f;
    float a4 = 0.f, a5 = 0.f, a6 = 0.f, a7 = 0.f;
#pragma unroll 4
    for (int si = 0; si < 32; ++si) {
      uint4 u = *(const uint4*)(eb + (size_t)si * DD);
      float ws = u_s[sg * 32 + si];
      float2 p0 = bfx2(u.x), p1 = bfx2(u.y), p2 = bfx2(u.z), p3 = bfx2(u.w);
      a0 += ws * p0.x; a1 += ws * p0.y;
      a2 += ws * p1.x; a3 += ws * p1.y;
      a4 += ws * p2.x; a5 += ws * p2.y;
      a6 += ws * p3.x; a7 += ws * p3.y;
    }
    float* pr = &part[sg * 520 + dsl * 8];
    float4 lo = {a0, a1, a2, a3}, hi = {a4, a5, a6, a7};
    *(float4*)&pr[0] = lo;
    *(float4*)&pr[4] = hi;
  }
  __syncthreads();
  {
    float r = 0.f;
#pragma unroll
    for (int sg = 0; sg < 8; ++sg) r += part[sg * 520 + tid];
    ctxp[((size_t)b * 2 + shalf) * 512 + tid] = r;
  }
}

// ---------------------------------------------------------------------------
// K_gru: combine ctx halves (split-softmax alphas), dual hi/lo MFMA GRU,
// write h + h2, write normalized attention row for b = mh*32+dgrp.
// grid 128 = (mh 0..3) x (dgrp 0..31): 32 b x 16 d per block.
// ---------------------------------------------------------------------------
__global__ __launch_bounds__(1024) void gru_fused(
    const float* __restrict__ ctxp, unsigned short* __restrict__ h2g,
    const unsigned short* __restrict__ Wih3, const unsigned short* __restrict__ Whh3,
    float* __restrict__ out_hT, const float* __restrict__ target,
    const float* __restrict__ W_ih, const float* __restrict__ b_ih,
    const float* __restrict__ b_hh, const float* __restrict__ stats,
    const float* __restrict__ uw, float* __restrict__ out_attn, int t) {
  const int blk = blockIdx.x, tid = threadIdx.x;
  const int w = tid >> 6, l = tid & 63, lm = l & 15, kg = l >> 4;
  const int mh = blk >> 5, dgrp = blk & 31;

  __shared__ unsigned short Ach[32 * 72];
  __shared__ unsigned short Acl[32 * 72];
  __shared__ unsigned short Ahh[32 * 72];
  __shared__ unsigned short Ahl[32 * 72];
  __shared__ unsigned short Bih[48 * 72];
  __shared__ unsigned short Bhh[48 * 72];
  __shared__ float als[64];

  if (tid < 32) {
    const int bb = mh * 32 + tid;
    float m0 = stats[bb * 4], l0 = stats[bb * 4 + 1];
    float m1 = stats[bb * 4 + 2], l1 = stats[bb * 4 + 3];
    float M = fmaxf(m0, m1);
    float iZ = 1.f / (l0 * __expf(m0 - M) + l1 * __expf(m1 - M));
    als[tid * 2] = __expf(m0 - M) * iZ;
    als[tid * 2 + 1] = __expf(m1 - M) * iZ;
  }

  float wx[3][3], pbih[3], pbhh[3];
  if (w < 2) {
    const int d = dgrp * 16 + lm;
#pragma unroll
    for (int g = 0; g < 3; ++g) {
      const float* wp = W_ih + (size_t)(g * 512 + d) * (DD + OO) + DD;
      wx[g][0] = wp[0]; wx[g][1] = wp[1]; wx[g][2] = wp[2];
      pbih[g] = b_ih[g * 512 + d];
      pbhh[g] = b_hh[g * 512 + d];
    }
  }
  __syncthreads();

  // normalized attention row for this block's b (threads 896+, else idle)
  if (tid >= 896) {
    const int b_att = mh * 32 + dgrp;
    const float a0 = als[dgrp * 2], a1 = als[dgrp * 2 + 1];
    const float* up = uw + (size_t)b_att * SS;
    float* ao = out_attn + ((size_t)b_att * TT + t) * SS;
    const int i0 = (tid - 896) * 4;
#pragma unroll
    for (int i = i0; i < i0 + 4; ++i) ao[i] = up[i] * ((i < 256) ? a0 : a1);
  }

  f32x4 aci[3] = {};
  f32x4 agh[3] = {};
  for (int kc = 0; kc < 512; kc += 64) {
    if (tid < 256) {  // ctx combine (alphas) + hi/lo split: 8 elems/thread
      int r = tid >> 3, ko = (tid & 7) * 8;
      int b = mh * 32 + r;
      const float a0 = als[r * 2], a1 = als[r * 2 + 1];
      const float* p0 = &ctxp[((size_t)b * 2) * 512 + kc + ko];
      const float* p1 = &ctxp[((size_t)b * 2 + 1) * 512 + kc + ko];
      float4 c0a = *(const float4*)p0, c0b = *(const float4*)(p0 + 4);
      float4 c1a = *(const float4*)p1, c1b = *(const float4*)(p1 + 4);
      float v[8] = {a0 * c0a.x + a1 * c1a.x, a0 * c0a.y + a1 * c1a.y,
                    a0 * c0a.z + a1 * c1a.z, a0 * c0a.w + a1 * c1a.w,
                    a0 * c0b.x + a1 * c1b.x, a0 * c0b.y + a1 * c1b.y,
                    a0 * c0b.z + a1 * c1b.z, a0 * c0b.w + a1 * c1b.w};
      uint32_t H[4], L[4];
#pragma unroll
      for (int i = 0; i < 4; ++i) {
        unsigned short h0 = f2bf(v[2 * i]), h1 = f2bf(v[2 * i + 1]);
        unsigned short l0_ = f2bf(v[2 * i] - bf2f(h0));
        unsigned short l1_ = f2bf(v[2 * i + 1] - bf2f(h1));
        H[i] = (uint32_t)h0 | ((uint32_t)h1 << 16);
        L[i] = (uint32_t)l0_ | ((uint32_t)l1_ << 16);
      }
      *(uint4*)&Ach[r * 72 + ko] = *(uint4*)H;
      *(uint4*)&Acl[r * 72 + ko] = *(uint4*)L;
    } else if (tid < 512) {  // h hi/lo copy
      int u = tid - 256;
      int r = u >> 3, ko = (u & 7) * 8;
      int b = mh * 32 + r;
      *(uint4*)&Ahh[r * 72 + ko] =
          *(const uint4*)&h2g[(size_t)b * 1024 + kc + ko];
      *(uint4*)&Ahl[r * 72 + ko] =
          *(const uint4*)&h2g[(size_t)b * 1024 + 512 + kc + ko];
    } else if (tid < 896) {  // B slices
      int u = tid - 512;
      int r = u >> 3, ko = (u & 7) * 8;  // r < 48
      *(uint4*)&Bih[r * 72 + ko] =
          *(const uint4*)&Wih3[(size_t)(dgrp * 48 + r) * 512 + kc + ko];
      *(uint4*)&Bhh[r * 72 + ko] =
          *(const uint4*)&Whh3[(size_t)(dgrp * 48 + r) * 512 + kc + ko];
    }
    __syncthreads();
    if (w < 2) {
#pragma unroll
      for (int ks = 0; ks < 2; ++ks) {
        const int ao = (w * 16 + lm) * 72 + ks * 32 + kg * 8;
        bf16x8 ach_ = *(const bf16x8*)&Ach[ao];
        bf16x8 acl_ = *(const bf16x8*)&Acl[ao];
        bf16x8 ahh_ = *(const bf16x8*)&Ahh[ao];
        bf16x8 ahl_ = *(const bf16x8*)&Ahl[ao];
#pragma unroll
        for (int g = 0; g < 3; ++g) {
          const int bo = (g * 16 + lm) * 72 + ks * 32 + kg * 8;
          bf16x8 bi = *(const bf16x8*)&Bih[bo];
          bf16x8 bh = *(const bf16x8*)&Bhh[bo];
          aci[g] = __builtin_amdgcn_mfma_f32_16x16x32_bf16(ach_, bi, aci[g], 0, 0, 0);
          aci[g] = __builtin_amdgcn_mfma_f32_16x16x32_bf16(acl_, bi, aci[g], 0, 0, 0);
          agh[g] = __builtin_amdgcn_mfma_f32_16x16x32_bf16(ahh_, bh, agh[g], 0, 0, 0);
          agh[g] = __builtin_amdgcn_mfma_f32_16x16x32_bf16(ahl_, bh, agh[g], 0, 0, 0);
        }
      }
    }
    __syncthreads();
  }

  if (w < 2) {
    const int d = dgrp * 16 + lm;
#pragma unroll
    for (int rr = 0; rr < 4; ++rr) {
      const int b = mh * 32 + w * 16 + kg * 4 + rr;
      float x0 = 0.f, x1 = 0.f, x2 = 0.f;
      if (t > 0) {
        const float* xp = target + ((size_t)b * TT + (t - 1)) * OO;
        x0 = xp[0]; x1 = xp[1]; x2 = xp[2];
      }
      float ir = aci[0][rr] + pbih[0] + x0 * wx[0][0] + x1 * wx[0][1] + x2 * wx[0][2];
      float iz = aci[1][rr] + pbih[1] + x0 * wx[1][0] + x1 * wx[1][1] + x2 * wx[1][2];
      float in_ = aci[2][rr] + pbih[2] + x0 * wx[2][0] + x1 * wx[2][1] + x2 * wx[2][2];
      float hr = agh[0][rr] + pbhh[0];
      float hz = agh[1][rr] + pbhh[1];
      float hn = agh[2][rr] + pbhh[2];
      float r_ = sigmoid_fast(ir + hr);
      float z_ = sigmoid_fast(iz + hz);
      float n_ = tanh_fast(in_ + r_ * hn);
      float hold = out_hT[(size_t)b * DD + d];
      float hnew = (1.f - z_) * n_ + z_ * hold;
      out_hT[(size_t)b * DD + d] = hnew;
      unsigned short hhi = f2bf(hnew);
      h2g[(size_t)b * 1024 + d] = hhi;
      h2g[(size_t)b * 1024 + 512 + d] = f2bf(hnew - bf2f(hhi));
    }
  }
}

// tail: out_d[:, T-1] from final h
__global__ __launch_bounds__(512) void outproj_tail(
    const float* __restrict__ out_hT, const float* __restrict__ W_out,
    const float* __restrict__ b_out, float* __restrict__ out_d) {
  const int tid = threadIdx.x;
  const int b = tid >> 2, g4 = tid & 3;
  const float* hp = out_hT + (size_t)b * DD + g4 * 128;
#pragma unroll
  for (int o = 0; o < OO; ++o) {
    const float* wrow = W_out + (size_t)o * DD + g4 * 128;
    float acc = 0.f;
#pragma unroll 8
    for (int i = 0; i < 128; ++i) acc += hp[i] * wrow[i];
    acc += __shfl_down(acc, 2, 4);
    acc += __shfl_down(acc, 1, 4);
    if (g4 == 0) out_d[((size_t)b * TT + (TT - 1)) * OO + o] = acc + b_out[o];
  }
}

// ---------------------------------------------------------------------------
extern "C" void kernel_launch(void* const* d_in, const int* in_sizes, int n_in,
                              void* d_out, int out_size, void* d_ws, size_t ws_size,
                              hipStream_t stream) {
  const float* e_all  = (const float*)d_in[0];
  const float* e_last = (const float*)d_in[1];
  const float* target = (const float*)d_in[2];
  const float* Wa     = (const float*)d_in[3];
  const float* ba     = (const float*)d_in[4];
  const float* Ua     = (const float*)d_in[5];
  const float* bu     = (const float*)d_in[6];
  const float* Va_w   = (const float*)d_in[7];
  const float* W_ih   = (const float*)d_in[9];
  const float* b_ih   = (const float*)d_in[10];
  const float* W_hh   = (const float*)d_in[11];
  const float* b_hh   = (const float*)d_in[12];
  const float* W_out  = (const float*)d_in[13];
  const float* b_out  = (const float*)d_in[14];

  float* out      = (float*)d_out;
  float* out_d    = out;                         // [B,T,3]
  float* out_hT   = out + (size_t)BB * TT * OO;  // [1,B,D]  (live h, f32)
  float* out_attn = out_hT + (size_t)BB * DD;    // [B,T,S]

  // Workspace layout (138,940,416 B <= 139,479,040 B proven-safe):
  //   0           Uk2     67,108,864
  //   67,108,864  e_bf    67,108,864
  //   134,217,728 Wq2t       524,288   [512 k][512 j] bf16
  //   134,742,016 Wih3     1,572,864   [1536][512] bf16
  //   136,314,880 Whh3     1,572,864
  //   137,887,744 bq           2,048
  //   137,889,792 h2         262,144   [128][1024] bf16 (hi|lo) } Ua_bf
  //   138,151,936 uw         262,144   [128][512] f32           } alias
  //   138,414,080 ctxp       524,288   [128][2][512] f32
  //   138,938,368 stats        2,048   [128][4] f32
  char* wsB = (char*)d_ws;
  unsigned short* Uk2   = (unsigned short*)wsB;
  unsigned short* e_bfp = (unsigned short*)(wsB + 67108864);
  unsigned short* Wq2t  = (unsigned short*)(wsB + 134217728);
  unsigned short* Wih3  = (unsigned short*)(wsB + 134742016);
  unsigned short* Whh3  = (unsigned short*)(wsB + 136314880);
  float* bq             = (float*)(wsB + 137887744);
  unsigned short* h2    = (unsigned short*)(wsB + 137889792);
  float* uw             = (float*)(wsB + 138151936);
  float* ctxp           = (float*)(wsB + 138414080);
  float* stats          = (float*)(wsB + 138938368);
  unsigned short* Ua_bf = (unsigned short*)(wsB + 137889792);  // prologue alias

  prep_wq2t<<<(DD * DD) / 256, 256, 0, stream>>>(Wa, Wq2t);
  prep_wih3<<<(1536 * 512) / 256, 256, 0, stream>>>(W_ih, Wih3);
  prep_whh3<<<(1536 * 512) / 256, 256, 0, stream>>>(W_hh, Whh3);
  prep_bq<<<2, 256, 0, stream>>>(ba, bq);
  conv_bf<<<(BB * SS * DD) / (8 * 256), 256, 0, stream>>>(e_all, e_bfp);
  conv_bf<<<(DD * DD) / (8 * 256), 256, 0, stream>>>(Ua, Ua_bf);
  gemm_uk_mfma<<<dim3(DD / 128, (BB * SS) / 128), 256, 0, stream>>>(
      e_bfp, Ua_bf, bu, Uk2);
  init_h<<<(BB * DD) / 256, 256, 0, stream>>>(e_last, out_hT, h2);  // after gemm_uk (alias)

  for (int t = 0; t < TT; ++t) {
    attn_fused<<<257, 512, 0, stream>>>(Uk2, e_bfp, Wq2t, bq, Va_w, out_hT,
                                        ctxp, stats, uw, W_out, b_out, out_d, t);
    gru_fused<<<128, 1024, 0, stream>>>(ctxp, h2, Wih3, Whh3, out_hT, target,
                                        W_ih, b_ih, b_hh, stats, uw, out_attn, t);
  }
  outproj_tail<<<1, 512, 0, stream>>>(out_hT, W_out, b_out, out_d);
}

// Round 6
// 5523.350 us; speedup vs baseline: 1.0934x; 1.0934x over previous
//
#include <hip/hip_runtime.h>
#include <cstdint>

constexpr int BB = 128;   // batch
constexpr int SS = 512;   // source length
constexpr int DD = 512;   // hidden dim
constexpr int TT = 64;    // decode steps
constexpr int OO = 3;     // output dim

constexpr float C2LE = 2.8853900817779268f;  // 2*log2(e)

typedef __attribute__((ext_vector_type(8))) short bf16x8;
typedef __attribute__((ext_vector_type(4))) float f32x4;
typedef unsigned int u32x4 __attribute__((ext_vector_type(4)));

__device__ __forceinline__ float tanh_fast(float x) {
  float e = __expf(2.0f * x);
  return 1.0f - 2.0f / (e + 1.0f);
}
__device__ __forceinline__ float sigmoid_fast(float x) {
  return 1.0f / (1.0f + __expf(-x));
}
__device__ __forceinline__ unsigned short f2bf(float f) {
  uint32_t u = __float_as_uint(f);
  uint32_t r = (u + 0x7FFFu + ((u >> 16) & 1u)) >> 16;  // RNE
  return (unsigned short)r;
}
__device__ __forceinline__ float bf2f(unsigned short h) {
  return __uint_as_float((uint32_t)h << 16);
}
__device__ __forceinline__ float2 bfx2(uint32_t u) {
  float2 r;
  r.x = __uint_as_float(u << 16);
  r.y = __uint_as_float(u & 0xFFFF0000u);
  return r;
}
__device__ __forceinline__ float fexp2(float x) {
#if __has_builtin(__builtin_amdgcn_exp2f)
  return __builtin_amdgcn_exp2f(x);
#else
  return exp2f(x);
#endif
}
__device__ __forceinline__ float frcp(float x) {
#if __has_builtin(__builtin_amdgcn_rcpf)
  return __builtin_amdgcn_rcpf(x);
#else
  return 1.0f / x;
#endif
}

// LLC-coherent (agent-scope, L2-bypassing) accessors for cross-block exchange.
__device__ __forceinline__ void gstore(float* p, float v) {
  __hip_atomic_store(p, v, __ATOMIC_RELAXED, __HIP_MEMORY_SCOPE_AGENT);
}
__device__ __forceinline__ float gload(const float* p) {
  return __hip_atomic_load(p, __ATOMIC_RELAXED, __HIP_MEMORY_SCOPE_AGENT);
}

// Fence-free pair barrier: every wave drains its own stores (vmcnt), then one
// lane does a relaxed agent-scope arrive+spin on this pair's private 256-B line.
__device__ __forceinline__ void pair_barrier(unsigned int* cnt,
                                             unsigned int target) {
  asm volatile("s_waitcnt vmcnt(0)" ::: "memory");
  __syncthreads();
  if (threadIdx.x == 0) {
    __hip_atomic_fetch_add(cnt, 1u, __ATOMIC_RELAXED, __HIP_MEMORY_SCOPE_AGENT);
    while (__hip_atomic_load(cnt, __ATOMIC_RELAXED,
                             __HIP_MEMORY_SCOPE_AGENT) < target)
      __builtin_amdgcn_s_sleep(2);
  }
  __syncthreads();
}

// ---------------------------------------------------------------------------
// MFMA bf16 GEMM: Uk2 = bf16( C2LE * (e_bf @ Ua_bf^T + bu) )   [B*S x D]
// ---------------------------------------------------------------------------
__global__ __launch_bounds__(256) void gemm_uk_mfma(
    const unsigned short* __restrict__ A, const unsigned short* __restrict__ Bw,
    const float* __restrict__ bias, unsigned short* __restrict__ Uk) {
  __shared__ unsigned short Asb[128 * 40];
  __shared__ unsigned short Bsb[128 * 40];
  const int tid = threadIdx.x;
  const int m0 = blockIdx.y * 128, n0 = blockIdx.x * 128;
  const int w = tid >> 6, l = tid & 63;
  const int wr = w >> 1, wc = w & 1;
  const int lm = l & 15, kg = l >> 4;

  f32x4 acc[4][4] = {};

  for (int kc = 0; kc < 512; kc += 32) {
    uint4 av[2], bv[2];
#pragma unroll
    for (int p = 0; p < 2; ++p) {
      int u = tid + p * 256;
      int r = u >> 2, ko = (u & 3) * 8;
      av[p] = *(const uint4*)(A + (size_t)(m0 + r) * 512 + kc + ko);
      bv[p] = *(const uint4*)(Bw + (size_t)(n0 + r) * 512 + kc + ko);
    }
    __syncthreads();
#pragma unroll
    for (int p = 0; p < 2; ++p) {
      int u = tid + p * 256;
      int r = u >> 2, ko = (u & 3) * 8;
      *(uint4*)&Asb[r * 40 + ko] = av[p];
      *(uint4*)&Bsb[r * 40 + ko] = bv[p];
    }
    __syncthreads();
    bf16x8 af[4], bfr[4];
#pragma unroll
    for (int i = 0; i < 4; ++i) {
      af[i]  = *(const bf16x8*)&Asb[(wr * 64 + i * 16 + lm) * 40 + kg * 8];
      bfr[i] = *(const bf16x8*)&Bsb[(wc * 64 + i * 16 + lm) * 40 + kg * 8];
    }
#pragma unroll
    for (int i = 0; i < 4; ++i)
#pragma unroll
      for (int j = 0; j < 4; ++j)
        acc[i][j] = __builtin_amdgcn_mfma_f32_16x16x32_bf16(af[i], bfr[j],
                                                            acc[i][j], 0, 0, 0);
  }

  const int row_base = m0 + wr * 64;
  const int col_base = n0 + wc * 64;
#pragma unroll
  for (int j = 0; j < 4; ++j) {
    const int col = col_base + j * 16 + lm;
    const float bu = bias[col];
#pragma unroll
    for (int i = 0; i < 4; ++i) {
      const int r0 = row_base + i * 16 + kg * 4;
#pragma unroll
      for (int rr = 0; rr < 4; ++rr)
        Uk[(size_t)(r0 + rr) * 512 + col] = f2bf(C2LE * (acc[i][j][rr] + bu));
    }
  }
}

// fp32 -> bf16, 8 elems/thread
__global__ __launch_bounds__(256) void conv_bf(const float* __restrict__ in,
                                               unsigned short* __restrict__ outp) {
  size_t idx = ((size_t)blockIdx.x * 256 + threadIdx.x) * 8;
  const float4* p = (const float4*)(in + idx);
  float4 a = p[0], b = p[1];
  uint4 r;
  r.x = f2bf(a.x) | ((uint32_t)f2bf(a.y) << 16);
  r.y = f2bf(a.z) | ((uint32_t)f2bf(a.w) << 16);
  r.z = f2bf(b.x) | ((uint32_t)f2bf(b.y) << 16);
  r.w = f2bf(b.z) | ((uint32_t)f2bf(b.w) << 16);
  *(uint4*)(outp + idx) = r;
}

// Wq2t[k*512 + j] = bf16(C2LE * Wa[j][k])   (k-major)
__global__ void prep_wq2t(const float* __restrict__ Wa,
                          unsigned short* __restrict__ Wq2t) {
  int idx = blockIdx.x * 256 + threadIdx.x;  // k*512 + j
  int k = idx >> 9, j = idx & 511;
  Wq2t[idx] = f2bf(C2LE * Wa[(size_t)j * DD + k]);
}

// WihT[k*1536 + col] = bf16(W_ih[col][k]),  col = gate*512 + d  (k-major)
__global__ void prep_wihT(const float* __restrict__ W_ih,
                          unsigned short* __restrict__ WihT) {
  int idx = blockIdx.x * 256 + threadIdx.x;  // 512*1536
  int k = idx / 1536, col = idx % 1536;
  WihT[idx] = f2bf(W_ih[(size_t)col * (DD + OO) + k]);
}

// WhhT same, from W_hh (ld 512)
__global__ void prep_whhT(const float* __restrict__ Whh,
                          unsigned short* __restrict__ WhhT) {
  int idx = blockIdx.x * 256 + threadIdx.x;  // 512*1536
  int k = idx / 1536, col = idx % 1536;
  WhhT[idx] = f2bf(Whh[(size_t)col * DD + k]);
}

__global__ void prep_bq(const float* __restrict__ ba, float* __restrict__ bq) {
  int j = blockIdx.x * 256 + threadIdx.x;  // 512
  bq[j] = C2LE * ba[j];
}

// ---------------------------------------------------------------------------
// Persistent pair decode: 256 blocks = (b, half) x 1024 threads, whole T-loop.
// 3 fence-free pair barriers per step. Cross-block data via agent-scope (LLC)
// loads/stores only; weights stay hot in per-XCD L2 (streams use NT ops).
// ---------------------------------------------------------------------------
__global__ __launch_bounds__(1024, 1) void decode_pairs(
    const unsigned short* __restrict__ Uk2, const unsigned short* __restrict__ e_bf,
    const unsigned short* __restrict__ Wq2t, const unsigned short* __restrict__ WihT,
    const unsigned short* __restrict__ WhhT, const float* __restrict__ bq,
    const float* __restrict__ W_ih, const float* __restrict__ b_ih,
    const float* __restrict__ b_hh, const float* __restrict__ e_last,
    const float* __restrict__ target, const float* __restrict__ Va_w,
    const float* __restrict__ W_out, const float* __restrict__ b_out,
    float* __restrict__ ctxp, char* __restrict__ bars,
    float* __restrict__ out_d, float* __restrict__ out_hT,
    float* __restrict__ out_attn) {
  const int blk = blockIdx.x, tid = threadIdx.x;
  const int b = blk >> 1, half = blk & 1;
  char* bar_base = bars + (size_t)b * 256;
  unsigned int* cnt = (unsigned int*)bar_base;
  float* stat4 = (float*)(bar_base + 16);  // [m0, l0, m1, l1]
  unsigned int bc = 0;

  __shared__ float va_s[528];
  __shared__ float qv_s[528];
  __shared__ float h_s[512];
  __shared__ float pd_s[512];
  __shared__ float u_s[256];
  __shared__ float w_s[256];
  __shared__ float red_s[16];
  __shared__ float part[16 * 520];
  __shared__ float ctx_s[512];
  __shared__ float gis[768];
  __shared__ float ghs[768];

  // persistent per-thread preloads: x-weights + biases for owned (gate, d)
  float wxr0 = 0.f, wxr1 = 0.f, wxr2 = 0.f, bihr = 0.f, bhhr = 0.f;
  if (tid < 768) {
    const int gate = tid >> 8, dl = tid & 255;
    const int row = gate * 512 + half * 256 + dl;
    const float* wp = W_ih + (size_t)row * (DD + OO) + DD;
    wxr0 = wp[0]; wxr1 = wp[1]; wxr2 = wp[2];
    bihr = b_ih[row]; bhhr = b_hh[row];
  }
  if (tid < 512) va_s[(tid >> 7) * 132 + (tid & 127)] = Va_w[tid];
  __syncthreads();

  for (int t = 0; t < TT; ++t) {
    // ---------------- P1: load h, full q2 GEMV, scores, local softmax -----
    if (tid < 512) {
      h_s[tid] = (t == 0) ? e_last[(size_t)b * 512 + tid]
                          : gload(out_hT + (size_t)b * 512 + tid);
    }
    __syncthreads();
    {
      const int col = tid & 511, kb = tid >> 9;
      const unsigned short* wp = Wq2t + (size_t)(kb * 256) * 512 + col;
      const float* hb = &h_s[kb * 256];
      float acc = 0.f;
      for (int k0 = 0; k0 < 256; k0 += 8) {
        float4 hv0 = *(const float4*)&hb[k0];
        float4 hv1 = *(const float4*)&hb[k0 + 4];
        acc += hv0.x * bf2f(wp[(size_t)(k0 + 0) * 512]);
        acc += hv0.y * bf2f(wp[(size_t)(k0 + 1) * 512]);
        acc += hv0.z * bf2f(wp[(size_t)(k0 + 2) * 512]);
        acc += hv0.w * bf2f(wp[(size_t)(k0 + 3) * 512]);
        acc += hv1.x * bf2f(wp[(size_t)(k0 + 4) * 512]);
        acc += hv1.y * bf2f(wp[(size_t)(k0 + 5) * 512]);
        acc += hv1.z * bf2f(wp[(size_t)(k0 + 6) * 512]);
        acc += hv1.w * bf2f(wp[(size_t)(k0 + 7) * 512]);
      }
      if (kb) pd_s[col] = acc;
      __syncthreads();
      if (!kb) {
        float q = acc + pd_s[col] + bq[col];
        qv_s[(col >> 7) * 132 + (col & 127)] = q;
      }
      // out_d[t-1] on half-0 (h_s is h after step t-1), threads 512..703
      if (half == 0 && t > 0 && tid >= 512 && tid < 704) {
        const int o = (tid - 512) >> 6, ln = tid & 63;
        const float* wrow = W_out + (size_t)o * DD;
        float a = 0.f;
        for (int i = ln; i < DD; i += 64) a += h_s[i] * wrow[i];
#pragma unroll
        for (int off = 32; off; off >>= 1) a += __shfl_xor(a, off);
        if (ln == 0)
          out_d[((size_t)b * TT + (t - 1)) * OO + o] = a + b_out[o];
      }
    }
    __syncthreads();
    {  // scores for own 256 s: 4 threads/s x 128 d
      const int sl = tid >> 2, qp = tid & 3;
      const u32x4* up = (const u32x4*)(Uk2 +
          ((size_t)b * SS + half * 256 + sl) * DD + qp * 128);
      const float* qb = &qv_s[qp * 132];
      const float* vb = &va_s[qp * 132];
      float acc = 0.f;
#pragma unroll 4
      for (int j = 0; j < 16; ++j) {
        u32x4 u = __builtin_nontemporal_load(up + j);
        float4 q0 = *(const float4*)&qb[j * 8], q1 = *(const float4*)&qb[j * 8 + 4];
        float4 v0 = *(const float4*)&vb[j * 8], v1 = *(const float4*)&vb[j * 8 + 4];
        float2 e0 = bfx2(u[0]), e1 = bfx2(u[1]), e2 = bfx2(u[2]), e3 = bfx2(u[3]);
        acc += v0.x * frcp(1.f + fexp2(q0.x + e0.x));
        acc += v0.y * frcp(1.f + fexp2(q0.y + e0.y));
        acc += v0.z * frcp(1.f + fexp2(q0.z + e1.x));
        acc += v0.w * frcp(1.f + fexp2(q0.w + e1.y));
        acc += v1.x * frcp(1.f + fexp2(q1.x + e2.x));
        acc += v1.y * frcp(1.f + fexp2(q1.y + e2.y));
        acc += v1.z * frcp(1.f + fexp2(q1.z + e3.x));
        acc += v1.w * frcp(1.f + fexp2(q1.w + e3.y));
      }
      acc += __shfl_xor(acc, 1);
      acc += __shfl_xor(acc, 2);
      if (qp == 0) u_s[sl] = -2.f * acc;  // logit (up to +const)
    }
    __syncthreads();
    {  // local softmax stats over own 256
      const int w4 = tid >> 6;
      float y = (tid < 256) ? u_s[tid] : -3.0e38f;
      float m = y;
#pragma unroll
      for (int off = 32; off; off >>= 1) m = fmaxf(m, __shfl_xor(m, off));
      if (w4 < 4 && (tid & 63) == 0) red_s[w4] = m;
      __syncthreads();
      const float gm =
          fmaxf(fmaxf(red_s[0], red_s[1]), fmaxf(red_s[2], red_s[3]));
      float e = (tid < 256) ? __expf(y - gm) : 0.f;
      float sm = e;
#pragma unroll
      for (int off = 32; off; off >>= 1) sm += __shfl_xor(sm, off);
      if (w4 < 4 && (tid & 63) == 0) red_s[8 + w4] = sm;
      __syncthreads();
      if (tid < 256) u_s[tid] = e;
      if (tid == 0) {
        gstore(&stat4[half * 2], gm);
        gstore(&stat4[half * 2 + 1],
               red_s[8] + red_s[9] + red_s[10] + red_s[11]);
      }
    }
    pair_barrier(cnt, 2 * (++bc));

    // ---------------- P2: finalize softmax, attn out, ctx partial ---------
    if (tid == 0) {
      red_s[8] = gload(&stat4[0]);
      red_s[9] = gload(&stat4[1]);
      red_s[10] = gload(&stat4[2]);
      red_s[11] = gload(&stat4[3]);
    }
    __syncthreads();
    {
      const float m0 = red_s[8], l0 = red_s[9], m1 = red_s[10], l1 = red_s[11];
      const float M = fmaxf(m0, m1);
      const float invZ = frcp(l0 * __expf(m0 - M) + l1 * __expf(m1 - M));
      const float al = __expf((half ? m1 : m0) - M) * invZ;
      if (tid < 256) {
        float wv = u_s[tid] * al;
        w_s[tid] = wv;
        __builtin_nontemporal_store(
            wv, out_attn + ((size_t)b * TT + t) * SS + half * 256 + tid);
      }
    }
    __syncthreads();
    {  // ctx partial over own 256 s: 16 s-groups x 64 d-slots of 8
      const int dsl = tid & 63, sg = tid >> 6;
      const unsigned short* eb =
          e_bf + ((size_t)b * SS + half * 256 + sg * 16) * DD + dsl * 8;
      float a0 = 0.f, a1 = 0.f, a2 = 0.f, a3 = 0.f;
      float a4 = 0.f, a5 = 0.f, a6 = 0.f, a7 = 0.f;
#pragma unroll 4
      for (int si = 0; si < 16; ++si) {
        u32x4 u = __builtin_nontemporal_load((const u32x4*)(eb + (size_t)si * DD));
        float ws = w_s[sg * 16 + si];
        float2 p0 = bfx2(u[0]), p1 = bfx2(u[1]), p2 = bfx2(u[2]), p3 = bfx2(u[3]);
        a0 += ws * p0.x; a1 += ws * p0.y;
        a2 += ws * p1.x; a3 += ws * p1.y;
        a4 += ws * p2.x; a5 += ws * p2.y;
        a6 += ws * p3.x; a7 += ws * p3.y;
      }
      float* pr = &part[sg * 520 + dsl * 8];
      float4 lo = {a0, a1, a2, a3}, hi = {a4, a5, a6, a7};
      *(float4*)&pr[0] = lo;
      *(float4*)&pr[4] = hi;
    }
    __syncthreads();
    if (tid < 512) {
      float r = 0.f;
#pragma unroll
      for (int sg = 0; sg < 16; ++sg) r += part[sg * 520 + tid];
      gstore(&ctxp[((size_t)b * 2 + half) * 512 + tid], r);
    }
    pair_barrier(cnt, 2 * (++bc));

    // ---------------- P3: gi/gh GEMV (own d-half) + GRU -------------------
    if (tid < 512)
      ctx_s[tid] = gload(&ctxp[(size_t)b * 2 * 512 + tid]) +
                   gload(&ctxp[((size_t)b * 2 + 1) * 512 + tid]);
    __syncthreads();
    if (tid < 768) {
      const int gate = tid >> 8, dl = tid & 255;
      const int col = gate * 512 + half * 256 + dl;
      const unsigned short* wi = WihT + col;
      const unsigned short* wh = WhhT + col;
      float ai = 0.f, ah = 0.f;
      for (int k0 = 0; k0 < 512; k0 += 8) {
        float4 c0 = *(const float4*)&ctx_s[k0];
        float4 c1 = *(const float4*)&ctx_s[k0 + 4];
        float4 h0 = *(const float4*)&h_s[k0];
        float4 h1 = *(const float4*)&h_s[k0 + 4];
        ai += c0.x * bf2f(wi[(size_t)(k0 + 0) * 1536]);
        ah += h0.x * bf2f(wh[(size_t)(k0 + 0) * 1536]);
        ai += c0.y * bf2f(wi[(size_t)(k0 + 1) * 1536]);
        ah += h0.y * bf2f(wh[(size_t)(k0 + 1) * 1536]);
        ai += c0.z * bf2f(wi[(size_t)(k0 + 2) * 1536]);
        ah += h0.z * bf2f(wh[(size_t)(k0 + 2) * 1536]);
        ai += c0.w * bf2f(wi[(size_t)(k0 + 3) * 1536]);
        ah += h0.w * bf2f(wh[(size_t)(k0 + 3) * 1536]);
        ai += c1.x * bf2f(wi[(size_t)(k0 + 4) * 1536]);
        ah += h1.x * bf2f(wh[(size_t)(k0 + 4) * 1536]);
        ai += c1.y * bf2f(wi[(size_t)(k0 + 5) * 1536]);
        ah += h1.y * bf2f(wh[(size_t)(k0 + 5) * 1536]);
        ai += c1.z * bf2f(wi[(size_t)(k0 + 6) * 1536]);
        ah += h1.z * bf2f(wh[(size_t)(k0 + 6) * 1536]);
        ai += c1.w * bf2f(wi[(size_t)(k0 + 7) * 1536]);
        ah += h1.w * bf2f(wh[(size_t)(k0 + 7) * 1536]);
      }
      float x0 = 0.f, x1 = 0.f, x2 = 0.f;
      if (t > 0) {
        const float* xp = target + ((size_t)b * TT + (t - 1)) * OO;
        x0 = xp[0]; x1 = xp[1]; x2 = xp[2];
      }
      gis[tid] = ai + bihr + x0 * wxr0 + x1 * wxr1 + x2 * wxr2;
      ghs[tid] = ah + bhhr;
    }
    __syncthreads();
    if (tid < 256) {
      const int d = half * 256 + tid;
      float r_ = sigmoid_fast(gis[tid] + ghs[tid]);
      float z_ = sigmoid_fast(gis[256 + tid] + ghs[256 + tid]);
      float n_ = tanh_fast(gis[512 + tid] + r_ * ghs[512 + tid]);
      float hnew = (1.f - z_) * n_ + z_ * h_s[d];
      gstore(out_hT + (size_t)b * 512 + d, hnew);
    }
    pair_barrier(cnt, 2 * (++bc));
  }

  // ---- tail: out_d[:, T-1] from final h
  if (half == 0) {
    if (tid < 512) h_s[tid] = gload(out_hT + (size_t)b * 512 + tid);
    __syncthreads();
    if (tid < 192) {
      const int o = tid >> 6, ln = tid & 63;
      const float* wrow = W_out + (size_t)o * DD;
      float a = 0.f;
      for (int i = ln; i < DD; i += 64) a += h_s[i] * wrow[i];
#pragma unroll
      for (int off = 32; off; off >>= 1) a += __shfl_xor(a, off);
      if (ln == 0)
        out_d[((size_t)b * TT + (TT - 1)) * OO + o] = a + b_out[o];
    }
  }
}

// ---------------------------------------------------------------------------
extern "C" void kernel_launch(void* const* d_in, const int* in_sizes, int n_in,
                              void* d_out, int out_size, void* d_ws, size_t ws_size,
                              hipStream_t stream) {
  const float* e_all  = (const float*)d_in[0];
  const float* e_last = (const float*)d_in[1];
  const float* target = (const float*)d_in[2];
  const float* Wa     = (const float*)d_in[3];
  const float* ba     = (const float*)d_in[4];
  const float* Ua     = (const float*)d_in[5];
  const float* bu     = (const float*)d_in[6];
  const float* Va_w   = (const float*)d_in[7];
  const float* W_ih   = (const float*)d_in[9];
  const float* b_ih   = (const float*)d_in[10];
  const float* W_hh   = (const float*)d_in[11];
  const float* b_hh   = (const float*)d_in[12];
  const float* W_out  = (const float*)d_in[13];
  const float* b_out  = (const float*)d_in[14];

  float* out      = (float*)d_out;
  float* out_d    = out;                         // [B,T,3]
  float* out_hT   = out + (size_t)BB * TT * OO;  // [1,B,D]  (live h, f32)
  float* out_attn = out_hT + (size_t)BB * DD;    // [B,T,S]

  // Workspace layout (138,446,848 B <= 139,479,040 B proven-safe):
  //   0           Uk2     67,108,864
  //   67,108,864  e_bf    67,108,864
  //   134,217,728 Wq2t       524,288   [512 k][512 j] bf16
  //   134,742,016 WihT     1,572,864   [512 k][1536 col] bf16
  //   136,314,880 WhhT     1,572,864
  //   137,887,744 bq           2,048
  //   137,889,792 ctxp       524,288   [128][2][512] f32  } Ua_bf (prologue)
  //   138,414,080 bars        32,768   128 x 256 B        } aliases ctxp
  char* wsB = (char*)d_ws;
  unsigned short* Uk2   = (unsigned short*)wsB;
  unsigned short* e_bfp = (unsigned short*)(wsB + 67108864);
  unsigned short* Wq2t  = (unsigned short*)(wsB + 134217728);
  unsigned short* WihT  = (unsigned short*)(wsB + 134742016);
  unsigned short* WhhT  = (unsigned short*)(wsB + 136314880);
  float* bq             = (float*)(wsB + 137887744);
  float* ctxp           = (float*)(wsB + 137889792);
  char* bars            = wsB + 138414080;
  unsigned short* Ua_bf = (unsigned short*)(wsB + 137889792);  // prologue alias

  prep_wq2t<<<(DD * DD) / 256, 256, 0, stream>>>(Wa, Wq2t);
  prep_wihT<<<(512 * 1536) / 256, 256, 0, stream>>>(W_ih, WihT);
  prep_whhT<<<(512 * 1536) / 256, 256, 0, stream>>>(W_hh, WhhT);
  prep_bq<<<2, 256, 0, stream>>>(ba, bq);
  conv_bf<<<(BB * SS * DD) / (8 * 256), 256, 0, stream>>>(e_all, e_bfp);
  conv_bf<<<(DD * DD) / (8 * 256), 256, 0, stream>>>(Ua, Ua_bf);
  gemm_uk_mfma<<<dim3(DD / 128, (BB * SS) / 128), 256, 0, stream>>>(
      e_bfp, Ua_bf, bu, Uk2);

  hipMemsetAsync(bars, 0, 128 * 256, stream);

  decode_pairs<<<2 * BB, 1024, 0, stream>>>(
      Uk2, e_bfp, Wq2t, WihT, WhhT, bq, W_ih, b_ih, b_hh, e_last, target,
      Va_w, W_out, b_out, ctxp, bars, out_d, out_hT, out_attn);
}